// Round 4
// baseline (900.459 us; speedup 1.0000x reference)
//
#include <hip/hip_runtime.h>
#include <hip/hip_bf16.h>
#include <math.h>

#define NH 8
#define DKk 256
#define DVv 512
#define Bn 2
#define Tn 2048
#define HID 2048
#define EPSf 1e-5f

typedef __bf16 bf16x8 __attribute__((ext_vector_type(8)));
typedef float f32x4 __attribute__((ext_vector_type(4)));
typedef unsigned short us8 __attribute__((ext_vector_type(8)));
typedef unsigned short us4 __attribute__((ext_vector_type(4)));
using bf16 = __hip_bfloat16;
typedef unsigned short ushort_t;

__device__ __forceinline__ void gload_lds16(const void* g, void* lds_base) {
  __builtin_amdgcn_global_load_lds(
      (const __attribute__((address_space(1))) void*)g,
      (__attribute__((address_space(3))) void*)lds_base, 16, 0, 0);
}

__device__ __forceinline__ ushort_t f2bf_raw(float f) {
  bf16 h = __float2bfloat16(f);
  return *reinterpret_cast<ushort_t*>(&h);
}
__device__ __forceinline__ float bf2f_raw(ushort_t u) {
  union { unsigned int i; float f; } v; v.i = ((unsigned int)u) << 16; return v.f;
}

// ---------------- fp32 -> bf16 elementwise (vectorized x4) ----------------
__global__ void k_f32_to_bf16(const float4* __restrict__ in, ushort4* __restrict__ out, int n4) {
  int i = blockIdx.x * blockDim.x + threadIdx.x;
  if (i >= n4) return;
  float4 v = in[i];
  ushort4 o;
  o.x = f2bf_raw(v.x); o.y = f2bf_raw(v.y); o.z = f2bf_raw(v.z); o.w = f2bf_raw(v.w);
  out[i] = o;
}

// ---------------- W (K,N) fp32 -> WT (N,K) bf16 ----------------
__global__ void k_transpose_w(const float* __restrict__ W, bf16* __restrict__ WT, int K, int N) {
  __shared__ float t[32][33];
  int n0 = blockIdx.x * 32, k0 = blockIdx.y * 32;
  int tx = threadIdx.x, ty = threadIdx.y;
#pragma unroll
  for (int i = 0; i < 4; i++)
    t[ty + i * 8][tx] = W[(size_t)(k0 + ty + i * 8) * N + n0 + tx];
  __syncthreads();
#pragma unroll
  for (int i = 0; i < 4; i++)
    WT[(size_t)(n0 + ty + i * 8) * K + k0 + tx] = __float2bfloat16(t[tx][ty + i * 8]);
}

// ---------------- v -> vS: PV A-fragment layout ----------------
// Unit u = mt*64 + quad*16 + dvo (16B = 8 bf16). Element e holds
// v[b, kt*32 + quad*4 + (e&3) + 16*(e>>2), h, mt*16 + dvo]
// matching the PV MFMA k-slot bijection j(quad,e) = quad*4+(e&3)+16*(e>>2).
__global__ void k_build_vS(const ushort_t* __restrict__ v, ushort_t* __restrict__ vS) {
  __shared__ ushort_t t[32 * 520];
  const int tid = threadIdx.x;
  const int kt = blockIdx.x;
  const int bh = blockIdx.y;
  const int b = bh >> 3, h = bh & 7;
#pragma unroll
  for (int r = 0; r < 8; r++) {
    int j = r * 4 + (tid >> 6);
    int vec = tid & 63;
    us8 d = *(const us8*)(v + (((size_t)(b * Tn + kt * 32 + j) * NH + h) * DVv) + vec * 8);
    *(us8*)(&t[j * 520 + vec * 8]) = d;
  }
  __syncthreads();
#pragma unroll
  for (int u8 = 0; u8 < 8; u8++) {
    int u = u8 * 256 + tid;
    int mt = u >> 6;
    int quad = (u >> 4) & 3;
    int dv = mt * 16 + (u & 15);
    us8 o;
#pragma unroll
    for (int e = 0; e < 8; e++) {
      int j = quad * 4 + (e & 3) + 16 * (e >> 2);
      o[e] = t[j * 520 + dv];
    }
    *(us8*)(vS + ((size_t)(bh * 64 + kt) * 2048 + u) * 8) = o;
  }
}

// ---------------- RoPE in-place on bf16 (b,t,h,dk), scale folded ----------------
__global__ void k_rope(bf16* __restrict__ x, float scale) {
  int tid = blockIdx.x * 256 + threadIdx.x;
  int i = tid & 127;
  int h = (tid >> 7) & 7;
  int t = (tid >> 10) & (Tn - 1);
  int b = tid >> 21;
  float inv = exp2f(-(float)i * (13.287712379549449f / 128.0f));
  float ang = (float)t * inv;
  float s, c;
  sincosf(ang, &s, &c);
  size_t base = ((size_t)(b * Tn + t) * NH + h) * DKk + i;
  float x1 = __bfloat162float(x[base]);
  float x2 = __bfloat162float(x[base + 128]);
  x[base]       = __float2bfloat16((x1 * c - x2 * s) * scale);
  x[base + 128] = __float2bfloat16((x2 * c + x1 * s) * scale);
}

// ---------------- m97-style GEMM: C(M,N) = A(M,K) @ BT(N,K)^T ----------------
template <bool OUT_BF16>
__global__ __launch_bounds__(256) void k_gemm(const bf16* __restrict__ A, const bf16* __restrict__ BT,
                                              void* __restrict__ Cout, int M, int N, int K) {
  __shared__ __align__(16) bf16 a_lds[128 * 32];
  __shared__ __align__(16) bf16 b_lds[128 * 32];
  const int tid = threadIdx.x;
  const int l = tid & 63;
  const int w = tid >> 6;
  const int wr = w >> 1, wc = w & 1;
  const int m0 = blockIdx.y * 128, n0 = blockIdx.x * 128;
  const int quad = l >> 4, c16 = l & 15;

  const int lrow = l >> 2;
  const int loff = (l & 3) * 16;
  const char* aG0 = (const char*)(A + (size_t)(m0 + w * 32 + lrow) * K) + loff;
  const char* aG1 = (const char*)(A + (size_t)(m0 + w * 32 + 16 + lrow) * K) + loff;
  const char* bG0 = (const char*)(BT + (size_t)(n0 + w * 32 + lrow) * K) + loff;
  const char* bG1 = (const char*)(BT + (size_t)(n0 + w * 32 + 16 + lrow) * K) + loff;
  char* aL0 = (char*)a_lds + w * 2048;
  char* aL1 = (char*)a_lds + w * 2048 + 1024;
  char* bL0 = (char*)b_lds + w * 2048;
  char* bL1 = (char*)b_lds + w * 2048 + 1024;

  f32x4 acc[4][4];
  const f32x4 fz = {0.f, 0.f, 0.f, 0.f};
#pragma unroll
  for (int r = 0; r < 4; r++)
#pragma unroll
    for (int c = 0; c < 4; c++) acc[r][c] = fz;

  for (int k0 = 0; k0 < K; k0 += 32) {
    __syncthreads();
    size_t kb = (size_t)k0 * 2;
    gload_lds16(aG0 + kb, aL0);
    gload_lds16(aG1 + kb, aL1);
    gload_lds16(bG0 + kb, bL0);
    gload_lds16(bG1 + kb, bL1);
    __syncthreads();
    bf16x8 af[4], bfv[4];
#pragma unroll
    for (int r = 0; r < 4; r++)
      af[r] = *(const bf16x8*)(a_lds + (wr * 64 + r * 16 + c16) * 32 + quad * 8);
#pragma unroll
    for (int c = 0; c < 4; c++)
      bfv[c] = *(const bf16x8*)(b_lds + (wc * 64 + c * 16 + c16) * 32 + quad * 8);
#pragma unroll
    for (int r = 0; r < 4; r++)
#pragma unroll
      for (int c = 0; c < 4; c++)
        acc[r][c] = __builtin_amdgcn_mfma_f32_16x16x32_bf16(af[r], bfv[c], acc[r][c], 0, 0, 0);
  }

#pragma unroll
  for (int r = 0; r < 4; r++)
#pragma unroll
    for (int c = 0; c < 4; c++)
#pragma unroll
      for (int rr = 0; rr < 4; rr++) {
        int m = m0 + wr * 64 + r * 16 + quad * 4 + rr;
        int n = n0 + wc * 64 + c * 16 + c16;
        float val = acc[r][c][rr];
        if (OUT_BF16) ((bf16*)Cout)[(size_t)m * N + n] = __float2bfloat16(val);
        else          ((float*)Cout)[(size_t)m * N + n] = val;
      }
}

// ---------------- Retention v2: S^T / O^T form, P stays in registers ----------------
// Wave w owns i-group q0+w*16..+15 end-to-end.
// QK: S^T = K·Q^T (A = k LDS tile, B = q regs) -> C-layout col=i (lane), row=j.
// Decay+pack in regs -> PV B-frag via k-slot bijection j(quad,e)=quad*4+(e&3)+16*(e>>2).
// PV: O^T += V^T·P^T (A = vS direct from L2, B = packed P) -> col=i, rows=dv.
// One barrier per kt-step; k double-buffered, prefetch issued right after barrier.
__global__ __launch_bounds__(256, 2) void k_retention(const bf16* __restrict__ q, const bf16* __restrict__ k,
                                                      const char* __restrict__ vS, const bf16* __restrict__ g,
                                                      const float* __restrict__ gnw, bf16* __restrict__ X) {
  __shared__ __align__(16) char k_lds[2][16384];  // [32 j][512B], 16B-chunk XOR swizzle

  const int tid = threadIdx.x;
  const int l = tid & 63, w = tid >> 6;
  const int quad = l >> 4, c16 = l & 15;

  const int bid = blockIdx.x;
  const int xcd = bid & 7, slot = bid >> 3;
  const int bh = xcd + 8 * (slot & 1);
  const int b = bh >> 3, h = bh & 7;
  const int qt = 31 - (slot >> 1);   // longest blocks first
  const int q0 = qt * 64;
  const int iglob = q0 + w * 16 + c16;

  // q B-frags: lane c16 = i, elems = dk c*32+quad*8..+7
  bf16x8 qf[8];
  {
    const bf16* qrow = q + ((size_t)(b * Tn + iglob) * NH + h) * DKk + quad * 8;
#pragma unroll
    for (int c = 0; c < 8; c++) qf[c] = *(const bf16x8*)(qrow + c * 32);
  }

  const float log2g = log2f(1.0f - exp2f(-5.0f - (float)h));
  float Er[2][4];
#pragma unroll
  for (int jt = 0; jt < 2; jt++)
#pragma unroll
    for (int r = 0; r < 4; r++)
      Er[jt][r] = exp2f(-log2g * (float)(jt * 16 + quad * 4 + r));

  f32x4 acc[32];
  const f32x4 fz = {0.f, 0.f, 0.f, 0.f};
#pragma unroll
  for (int mt = 0; mt < 32; mt++) acc[mt] = fz;

  const int ktmax = 2 * qt + 1;
  const float Dcut = 30.0f / (-log2g);
  const int kt0 = (int)fmaxf(0.0f, floorf(((float)q0 - Dcut) * (1.0f / 32.0f)));

  const char* kbase = (const char*)k + ((size_t)b * Tn * NH + h) * DKk * 2;
  const int jrow = l >> 5;          // 0/1 within staging instr
  const int cslot = l & 31;         // 16B slot within row

  // stage k tile kt into buffer bsel (16 instrs, 4 per wave; 1 KB each = 2 rows)
#define STAGE_K(KT, BSEL)                                                              \
  {                                                                                    \
    _Pragma("unroll")                                                                  \
    for (int i = 0; i < 4; i++) {                                                      \
      int instr = w * 4 + i;                                                           \
      int j = instr * 2 + jrow;                                                        \
      int chunk_g = cslot ^ (j & 7);                                                   \
      const char* gp = kbase + (size_t)((KT) * 32 + j) * (NH * DKk * 2) + chunk_g * 16;\
      gload_lds16(gp, (char*)k_lds[BSEL] + instr * 1024);                              \
    }                                                                                  \
  }

  STAGE_K(kt0, 0);

  int bsel = 0;
  for (int kt = kt0; kt <= ktmax; kt++, bsel ^= 1) {
    __syncthreads();                     // buf[bsel] staged (prev iter / preloop)
    if (kt < ktmax) STAGE_K(kt + 1, bsel ^ 1);  // prefetch; drained at NEXT barrier

    // S^T: A = k rows (lane c16 = j within jt*16), B = qf
    f32x4 sacc[2] = {fz, fz};
#pragma unroll
    for (int jt = 0; jt < 2; jt++)
#pragma unroll
      for (int c = 0; c < 8; c++) {
        const char* kp = (const char*)k_lds[bsel] + (jt * 16 + c16) * 512 +
                         (((c * 4 + quad) ^ (c16 & 7)) * 16);
        bf16x8 af = *(const bf16x8*)kp;
        sacc[jt] = __builtin_amdgcn_mfma_f32_16x16x32_bf16(af, qf[c], sacc[jt], 0, 0, 0);
      }

    // decay + causal mask + pack -> PV B-frag (in registers, no LDS)
    float Ei = exp2f(log2g * (float)(iglob - kt * 32));
    union { us8 u; bf16x8 v; } bp;
#pragma unroll
    for (int jt = 0; jt < 2; jt++)
#pragma unroll
      for (int r = 0; r < 4; r++) {
        int jg = kt * 32 + jt * 16 + quad * 4 + r;
        float val = (iglob >= jg) ? sacc[jt][r] * Ei * Er[jt][r] : 0.0f;
        bp.u[jt * 4 + r] = f2bf_raw(val);
      }

    // O^T += V^T · P^T : A-frags straight from L2-resident vS
    const char* vt = vS + (size_t)(bh * 64 + kt) * 32768;
#pragma unroll
    for (int mt = 0; mt < 32; mt++) {
      bf16x8 va = *(const bf16x8*)(vt + mt * 1024 + l * 16);
      acc[mt] = __builtin_amdgcn_mfma_f32_16x16x32_bf16(va, bp.v, acc[mt], 0, 0, 0);
    }
  }

  // RMS per i: in-lane over 128 dv + 2 shuffles across quads
  float s = 0.f;
#pragma unroll
  for (int mt = 0; mt < 32; mt++)
#pragma unroll
    for (int r = 0; r < 4; r++) { float v2 = acc[mt][r]; s += v2 * v2; }
  s += __shfl_xor(s, 16);
  s += __shfl_xor(s, 32);
  const float ss = rsqrtf(s * (1.0f / DVv) + EPSf);

  // epilogue: gate with silu(g), direct us4 (8B) stores; lane owns row iglob
  const ushort_t* grow = (const ushort_t*)g + ((size_t)(b * Tn + iglob) * NH + h) * DVv;
  ushort_t* xrow = (ushort_t*)X + ((size_t)(b * Tn + iglob) * NH + h) * DVv;
#pragma unroll
  for (int mt = 0; mt < 32; mt++) {
    int dv = mt * 16 + quad * 4;
    float4 gw = *(const float4*)(gnw + dv);
    us4 gv = *(const us4*)(grow + dv);
    us4 ov;
#pragma unroll
    for (int r = 0; r < 4; r++) {
      float gf = bf2f_raw(gv[r]);
      float gate = gf / (1.0f + expf(-gf));
      float gwr = (r == 0) ? gw.x : (r == 1) ? gw.y : (r == 2) ? gw.z : gw.w;
      ov[r] = f2bf_raw(acc[mt][r] * ss * gwr * gate);
    }
    *(us4*)(xrow + dv) = ov;
  }
}

extern "C" void kernel_launch(void* const* d_in, const int* in_sizes, int n_in,
                              void* d_out, int out_size, void* d_ws, size_t ws_size,
                              hipStream_t stream) {
  const float* hs  = (const float*)d_in[0];
  const float* Wq  = (const float*)d_in[1];
  const float* Wk  = (const float*)d_in[2];
  const float* Wv  = (const float*)d_in[3];
  const float* Wg  = (const float*)d_in[4];
  const float* Wo  = (const float*)d_in[5];
  const float* gnw = (const float*)d_in[6];
  float* out = (float*)d_out;
  char* ws = (char*)d_ws;

  bf16* hsb = (bf16*)(ws);                    // 16 MB
  bf16* WqT = (bf16*)(ws + 16777216);         //  8 MB
  bf16* WkT = (bf16*)(ws + 25165824);         //  8 MB
  bf16* WvT = (bf16*)(ws + 33554432);         // 16 MB
  bf16* WgT = (bf16*)(ws + 50331648);         // 16 MB
  char* vSb = ws;                              // alias hsb/WqT/WkT (32 MB, dead after GEMMs)
  bf16* WoT = (bf16*)(ws + 33554432);         // alias WvT (16 MB, dead after v GEMM)
  bf16* qb = (bf16*)(ws + 67108864);          // 16 MB
  bf16* kb = (bf16*)(ws + 83886080);          // 16 MB
  bf16* vb = (bf16*)(ws + 100663296);         // 32 MB
  bf16* gb = (bf16*)(ws + 134217728);         // 32 MB
  bf16* Xb = vb;                               // alias v (dead after vS build)

  dim3 tb(32, 8);

  k_f32_to_bf16<<<8192, 256, 0, stream>>>((const float4*)hs, (ushort4*)hsb, 2097152);
  k_transpose_w<<<dim3(HID / 32, HID / 32), tb, 0, stream>>>(Wq, WqT, HID, HID);
  k_transpose_w<<<dim3(HID / 32, HID / 32), tb, 0, stream>>>(Wk, WkT, HID, HID);
  k_transpose_w<<<dim3(NH * DVv / 32, HID / 32), tb, 0, stream>>>(Wv, WvT, HID, NH * DVv);
  k_transpose_w<<<dim3(NH * DVv / 32, HID / 32), tb, 0, stream>>>(Wg, WgT, HID, NH * DVv);
  k_gemm<true><<<dim3(16, 32), 256, 0, stream>>>(hsb, WqT, qb, 4096, 2048, 2048);
  k_gemm<true><<<dim3(16, 32), 256, 0, stream>>>(hsb, WkT, kb, 4096, 2048, 2048);
  k_gemm<true><<<dim3(32, 32), 256, 0, stream>>>(hsb, WvT, vb, 4096, 4096, 2048);
  k_gemm<true><<<dim3(32, 32), 256, 0, stream>>>(hsb, WgT, gb, 4096, 4096, 2048);
  k_rope<<<16384, 256, 0, stream>>>(qb, 0.0625f);
  k_rope<<<16384, 256, 0, stream>>>(kb, 1.0f);
  k_build_vS<<<dim3(64, 16), 256, 0, stream>>>((const ushort_t*)vb, (ushort_t*)vSb);
  k_transpose_w<<<dim3(HID / 32, NH * DVv / 32), tb, 0, stream>>>(Wo, WoT, NH * DVv, HID);
  k_retention<<<512, 256, 0, stream>>>(qb, kb, vSb, gb, gnw, Xb);
  k_gemm<false><<<dim3(16, 32), 256, 0, stream>>>(Xb, WoT, out, 4096, 2048, 4096);
}